// Round 2
// baseline (452.432 us; speedup 1.0000x reference)
//
#include <hip/hip_runtime.h>
#include <stdint.h>

#define NB 8
#define NC 20
#define NN 2000
#define NP 2048
#define IOU_THR 0.5f
#define SCORE_THR 0.1f

// ---------------------------------------------------------------------------
// K1: per-batch pairwise IoU bit matrix in UNSORTED index space.
// rowbits[b][i][w] : bit (j&31) of word w=(j>>5) set iff IoU(box_i, box_j) > 0.5
// Grid: NB * 32 blocks of 256 threads (4 waves); each wave does 16 rows.
// ---------------------------------------------------------------------------
__global__ __launch_bounds__(256) void k_iou_bits(const float* __restrict__ boxes,
                                                  uint32_t* __restrict__ rowbits) {
#pragma clang fp contract(off)
    int b = blockIdx.x >> 5;          // /32
    int g = blockIdx.x & 31;          // row group of 64
    __shared__ float x1s[NP], y1s[NP], x2s[NP], y2s[NP], ars[NP];
    for (int j = threadIdx.x; j < NP; j += 256) {
        float vx1 = 0.f, vy1 = 0.f, vx2 = 0.f, vy2 = 0.f;
        if (j < NN) {
            const float* p = boxes + ((size_t)b * NN + j) * 4;
            // ONNX layout [y1,x1,y2,x2] -> x1,y1,x2,y2
            vy1 = p[0]; vx1 = p[1]; vy2 = p[2]; vx2 = p[3];
        }
        x1s[j] = vx1; y1s[j] = vy1; x2s[j] = vx2; y2s[j] = vy2;
        ars[j] = (vx2 - vx1) * (vy2 - vy1);
    }
    __syncthreads();
    int wave = threadIdx.x >> 6;
    int lane = threadIdx.x & 63;
    for (int rr = 0; rr < 16; ++rr) {
        int i = g * 64 + wave * 16 + rr;          // wave-uniform
        if (i >= NN) continue;
        float xi1 = x1s[i], yi1 = y1s[i], xi2 = x2s[i], yi2 = y2s[i], ai = ars[i];
        uint32_t myword = 0;
        for (int jj = 0; jj < 32; ++jj) {
            int j = jj * 64 + lane;               // lane-consecutive: conflict-free LDS
            bool sup = false;
            if (j < NN) {
                float ix1 = fmaxf(xi1, x1s[j]);
                float iy1 = fmaxf(yi1, y1s[j]);
                float ix2 = fminf(xi2, x2s[j]);
                float iy2 = fminf(yi2, y2s[j]);
                float iw = fmaxf(ix2 - ix1, 0.0f);
                float ih = fmaxf(iy2 - iy1, 0.0f);
                float inter = iw * ih;
                float uni = (ai + ars[j]) - inter;
                float iou = inter / fmaxf(uni, 1e-9f);
                sup = iou > IOU_THR;
            }
            unsigned long long m = __ballot(sup); // bits for j = jj*64 .. jj*64+63
            if ((lane >> 1) == jj)                // lanes 2jj, 2jj+1 keep the halves
                myword = (lane & 1) ? (uint32_t)(m >> 32) : (uint32_t)m;
        }
        rowbits[((size_t)b * NN + i) * 64 + lane] = myword;
    }
}

// ---------------------------------------------------------------------------
// K2: per-(b,c) stable descending-score sort via 64-bit keys + bitonic in LDS.
// key = ((0xFFFFFFFF - float_bits(score)) << 32) | index     (valid)
//       ( 0xFFFFFFFF                      << 32) | index     (invalid)
// Ascending key == descending score, ties broken by ascending index (stable,
// matching jnp.argsort). Padding keys ~0ull sort to the tail (>= NN).
// ---------------------------------------------------------------------------
__global__ __launch_bounds__(256) void k_sort(const float* __restrict__ scores,
                                              uint64_t* __restrict__ skeys) {
    int bc = blockIdx.x;
    __shared__ uint64_t keys[NP];
    const float* sc = scores + (size_t)bc * NN;
    for (int i = threadIdx.x; i < NP; i += 256) {
        uint64_t k;
        if (i < NN) {
            float s = sc[i];
            uint32_t hi = (s > SCORE_THR) ? (0xFFFFFFFFu - __float_as_uint(s))
                                          : 0xFFFFFFFFu;
            k = ((uint64_t)hi << 32) | (uint32_t)i;
        } else {
            k = ~0ull;
        }
        keys[i] = k;
    }
    __syncthreads();
    for (int k = 2; k <= NP; k <<= 1) {
        for (int j = k >> 1; j > 0; j >>= 1) {
            for (int idx = threadIdx.x; idx < NP; idx += 256) {
                int l = idx ^ j;
                if (l > idx) {
                    uint64_t a = keys[idx], bb = keys[l];
                    bool up = ((idx & k) == 0);
                    if ((a > bb) == up) { keys[idx] = bb; keys[l] = a; }
                }
            }
            __syncthreads();
        }
    }
    for (int i = threadIdx.x; i < NN; i += 256)
        skeys[(size_t)bc * NN + i] = keys[i];
}

// ---------------------------------------------------------------------------
// K3: greedy scan, ONE WAVE per (b,c). Suppression state `removed` lives in
// unsorted space, one 32-bit word per lane (64*32 = 2048 >= NN bits).
// Invariant: once all kept rows of rank < i are applied, the first alive
// candidate at rank >= i is itself kept (nothing can suppress it anymore).
// So the serial chain is one coalesced 256B row-load + OR per KEPT box only.
// ---------------------------------------------------------------------------
__global__ __launch_bounds__(64) void k_nms(const uint64_t* __restrict__ skeys,
                                            const uint32_t* __restrict__ rowbits,
                                            int* __restrict__ out) {
    int bc = blockIdx.x;
    int b = bc / NC, c = bc % NC;
    int lane = threadIdx.x;
    uint32_t removed = 0;
    const uint32_t* rb = rowbits + (size_t)b * NN * 64;
    const uint64_t* sk = skeys + (size_t)bc * NN;
    int* o = out + (size_t)bc * NN * 3;

    for (int i0 = 0; i0 < NN; i0 += 64) {
        int i = i0 + lane;
        bool inb = i < NN;
        uint64_t key = inb ? sk[i] : ~0ull;
        uint32_t ord = (uint32_t)key;
        bool valid = inb && ((uint32_t)(key >> 32) != 0xFFFFFFFFu);
        uint32_t osafe = valid ? ord : 0u;
        uint32_t w = (uint32_t)__shfl((int)removed, (int)(osafe >> 5));
        bool alive = valid && !((w >> (osafe & 31)) & 1u);
        unsigned long long pend = __ballot(alive);
        uint64_t keptmask = 0ull;
        while (pend) {
            int t = __builtin_ctzll(pend);        // first alive == KEPT
            keptmask |= (1ull << t);
            uint32_t r = (uint32_t)__shfl((int)ord, t);
            removed |= rb[(size_t)r * 64 + lane]; // apply its suppression row
            w = (uint32_t)__shfl((int)removed, (int)(osafe >> 5));
            alive = valid && !((w >> (osafe & 31)) & 1u) && (lane > t);
            pend = __ballot(alive);
        }
        if (inb) {
            bool kept = (keptmask >> lane) & 1ull;
            int base = i * 3;
            o[base + 0] = kept ? b : -1;
            o[base + 1] = kept ? c : -1;
            o[base + 2] = kept ? (int)ord : -1;
        }
    }
}

// ---------------------------------------------------------------------------
extern "C" void kernel_launch(void* const* d_in, const int* in_sizes, int n_in,
                              void* d_out, int out_size, void* d_ws, size_t ws_size,
                              hipStream_t stream) {
    (void)in_sizes; (void)n_in; (void)out_size; (void)ws_size;
    const float* boxes  = (const float*)d_in[0];   // [NB, NN, 4]
    const float* scores = (const float*)d_in[1];   // [NB, NC, NN]
    int* out = (int*)d_out;                        // [NB, NC, NN, 3]

    uint32_t* rowbits = (uint32_t*)d_ws;                           // NB*NN*64 u32 = 4.10 MB
    uint64_t* skeys   = (uint64_t*)((char*)d_ws +
                                    (size_t)NB * NN * 64 * sizeof(uint32_t)); // NB*NC*NN u64 = 2.56 MB

    k_iou_bits<<<dim3(NB * 32), dim3(256), 0, stream>>>(boxes, rowbits);
    k_sort   <<<dim3(NB * NC), dim3(256), 0, stream>>>(scores, skeys);
    k_nms    <<<dim3(NB * NC), dim3(64),  0, stream>>>(skeys, rowbits, out);
}

// Round 5
// 272.368 us; speedup vs baseline: 1.6611x; 1.6611x over previous
//
#include <hip/hip_runtime.h>
#include <stdint.h>

#define NB 8
#define NC 20
#define NN 2000
#define NP 2048
#define IOU_THR 0.5f
#define SCORE_THR 0.1f
#define DEPTH 8   // speculative prefetch depth in k_nms

// ---------------------------------------------------------------------------
// K1: per-batch pairwise IoU bit matrix in UNSORTED index space.
// rowbits[b][i][w] : bit (j&31) of word w=(j>>5) set iff IoU(box_i, box_j) > 0.5
// Grid: NB * 32 blocks of 256 threads (4 waves); each wave does 16 rows.
// ---------------------------------------------------------------------------
__global__ __launch_bounds__(256) void k_iou_bits(const float* __restrict__ boxes,
                                                  uint32_t* __restrict__ rowbits) {
#pragma clang fp contract(off)
    int b = blockIdx.x >> 5;          // /32
    int g = blockIdx.x & 31;          // row group of 64
    __shared__ float x1s[NP], y1s[NP], x2s[NP], y2s[NP], ars[NP];
    for (int j = threadIdx.x; j < NP; j += 256) {
        float vx1 = 0.f, vy1 = 0.f, vx2 = 0.f, vy2 = 0.f;
        if (j < NN) {
            const float* p = boxes + ((size_t)b * NN + j) * 4;
            // ONNX layout [y1,x1,y2,x2] -> x1,y1,x2,y2
            vy1 = p[0]; vx1 = p[1]; vy2 = p[2]; vx2 = p[3];
        }
        x1s[j] = vx1; y1s[j] = vy1; x2s[j] = vx2; y2s[j] = vy2;
        ars[j] = (vx2 - vx1) * (vy2 - vy1);
    }
    __syncthreads();
    int wave = threadIdx.x >> 6;
    int lane = threadIdx.x & 63;
    for (int rr = 0; rr < 16; ++rr) {
        int i = g * 64 + wave * 16 + rr;          // wave-uniform
        if (i >= NN) continue;
        float xi1 = x1s[i], yi1 = y1s[i], xi2 = x2s[i], yi2 = y2s[i], ai = ars[i];
        uint32_t myword = 0;
        for (int jj = 0; jj < 32; ++jj) {
            int j = jj * 64 + lane;               // lane-consecutive: conflict-free LDS
            bool sup = false;
            if (j < NN) {
                float ix1 = fmaxf(xi1, x1s[j]);
                float iy1 = fmaxf(yi1, y1s[j]);
                float ix2 = fminf(xi2, x2s[j]);
                float iy2 = fminf(yi2, y2s[j]);
                float iw = fmaxf(ix2 - ix1, 0.0f);
                float ih = fmaxf(iy2 - iy1, 0.0f);
                float inter = iw * ih;
                float uni = (ai + ars[j]) - inter;
                float iou = inter / fmaxf(uni, 1e-9f);
                sup = iou > IOU_THR;
            }
            unsigned long long m = __ballot(sup); // bits for j = jj*64 .. jj*64+63
            if ((lane >> 1) == jj)                // lanes 2jj, 2jj+1 keep the halves
                myword = (lane & 1) ? (uint32_t)(m >> 32) : (uint32_t)m;
        }
        rowbits[((size_t)b * NN + i) * 64 + lane] = myword;
    }
}

// ---------------------------------------------------------------------------
// K2: per-(b,c) stable descending-score sort via 64-bit keys + bitonic in LDS.
// key = ((0xFFFFFFFF - float_bits(score)) << 32) | index     (valid)
//       ( 0xFFFFFFFF                      << 32) | index     (invalid)
// Ascending key == descending score, ties broken by ascending index (stable,
// matching jnp.argsort). Padding keys ~0ull sort to the tail (>= NN).
// 1024 threads: each of the 66 barrier-separated stages runs 2 strided
// sub-passes instead of 8 -> ~4x lower per-stage latency, same total work.
// ---------------------------------------------------------------------------
__global__ __launch_bounds__(1024) void k_sort(const float* __restrict__ scores,
                                               uint64_t* __restrict__ skeys) {
    int bc = blockIdx.x;
    __shared__ uint64_t keys[NP];
    const float* sc = scores + (size_t)bc * NN;
    for (int i = threadIdx.x; i < NP; i += 1024) {
        uint64_t k;
        if (i < NN) {
            float s = sc[i];
            uint32_t hi = (s > SCORE_THR) ? (0xFFFFFFFFu - __float_as_uint(s))
                                          : 0xFFFFFFFFu;
            k = ((uint64_t)hi << 32) | (uint32_t)i;
        } else {
            k = ~0ull;
        }
        keys[i] = k;
    }
    __syncthreads();
    for (int k = 2; k <= NP; k <<= 1) {
        for (int j = k >> 1; j > 0; j >>= 1) {
            for (int idx = threadIdx.x; idx < NP; idx += 1024) {
                int l = idx ^ j;
                if (l > idx) {
                    uint64_t a = keys[idx], bb = keys[l];
                    bool up = ((idx & k) == 0);
                    if ((a > bb) == up) { keys[idx] = bb; keys[l] = a; }
                }
            }
            __syncthreads();
        }
    }
    for (int i = threadIdx.x; i < NN; i += 1024)
        skeys[(size_t)bc * NN + i] = keys[i];
}

// ---------------------------------------------------------------------------
// K3: greedy scan, ONE WAVE per (b,c), speculative depth-8 prefetch.
//
// The serial chain of greedy NMS is one suppression-row application per KEPT
// box. Round-2 counters: K~244 kept/class, every row load missed to HBM
// (FETCH ~= 160*K*256B) -> 2.5K cycles per serial step. Two fixes:
//  (1) XCD locality: b = blockIdx%8, so all 20 classes of batch b run on the
//      same XCD and the batch's 512KB rowbits slice stays in that XCD's L2.
//  (2) Speculation: the suppression graph is sparse (each kept row kills ~7
//      of ~2000 later candidates), so the next DEPTH alive candidates are
//      nearly always all kept. Load all DEPTH rows in parallel (one latency),
//      then validate serially in-register: candidate k is kept iff its bit is
//      clear in the OR of rows of batch candidates kept before it (exactly
//      greedy order). Wrong speculations just waste a cheap load.
//
// Suppression state `removed` lives in unsorted space, one 32-bit word per
// lane (64*32 = 2048 >= NN bits).
// ---------------------------------------------------------------------------
__global__ __launch_bounds__(64) void k_nms(const uint64_t* __restrict__ skeys,
                                            const uint32_t* __restrict__ rowbits,
                                            int* __restrict__ out) {
    int bid = blockIdx.x;
    int b = bid & 7;                  // same batch -> same XCD (round-robin heuristic)
    int c = bid >> 3;                 // 0..19
    int bc = b * NC + c;
    int lane = threadIdx.x;
    uint32_t removed = 0;
    const uint32_t* rb = rowbits + (size_t)b * NN * 64;
    const uint64_t* sk = skeys + (size_t)bc * NN;
    int* o = out + (size_t)bc * NN * 3;

    for (int i0 = 0; i0 < NN; i0 += 64) {
        int i = i0 + lane;
        bool inb = i < NN;
        uint64_t key = inb ? sk[i] : ~0ull;
        uint32_t ord = (uint32_t)key;
        bool valid = inb && ((uint32_t)(key >> 32) != 0xFFFFFFFFu);
        uint32_t osafe = valid ? ord : 0u;
        uint32_t wsel = osafe >> 5, bsel = osafe & 31;
        uint32_t w = (uint32_t)__shfl((int)removed, (int)wsel);
        bool alive = valid && !((w >> bsel) & 1u);
        unsigned long long pend = __ballot(alive);
        uint64_t keptmask = 0ull;

        while (pend) {
            // --- extract first DEPTH alive positions (wave-uniform scalars) ---
            int t[DEPTH];
            unsigned long long p = pend;
#pragma unroll
            for (int k = 0; k < DEPTH; ++k) {
                t[k] = p ? __builtin_ctzll(p) : -1;
                if (p) p &= p - 1;
            }
            // --- their unsorted box indices (shfl; absent slots alias t[0]) ---
            uint32_t r[DEPTH];
#pragma unroll
            for (int k = 0; k < DEPTH; ++k) {
                int src = (t[k] >= 0) ? t[k] : t[0];
                r[k] = (uint32_t)__shfl((int)ord, src);
            }
            // --- issue ALL row loads back-to-back: DEPTH in flight, 1 latency ---
            uint32_t row[DEPTH];
#pragma unroll
            for (int k = 0; k < DEPTH; ++k)
                row[k] = rb[(size_t)r[k] * 64 + lane];
            // --- serial in-register validation (greedy order within batch) ---
            uint32_t acc = row[0];                 // t[0] is provably kept
            keptmask |= 1ull << t[0];
            int tlast = t[0];
#pragma unroll
            for (int k = 1; k < DEPTH; ++k) {
                if (t[k] >= 0) {                   // uniform branch
                    uint32_t ww = (uint32_t)__shfl((int)acc, (int)(r[k] >> 5));
                    if (!((ww >> (r[k] & 31)) & 1u)) {   // survived batch-kept rows
                        acc |= row[k];
                        keptmask |= 1ull << t[k];
                    }
                    tlast = t[k];                  // decided either way
                }
            }
            removed |= acc;
            // --- recompute alive for undecided lanes ---
            w = (uint32_t)__shfl((int)removed, (int)wsel);
            alive = valid && !((w >> bsel) & 1u) && (lane > tlast);
            pend = __ballot(alive);
        }

        if (inb) {
            bool kept = (keptmask >> lane) & 1ull;
            int base = i * 3;
            o[base + 0] = kept ? b : -1;
            o[base + 1] = kept ? c : -1;
            o[base + 2] = kept ? (int)ord : -1;
        }
    }
}

// ---------------------------------------------------------------------------
extern "C" void kernel_launch(void* const* d_in, const int* in_sizes, int n_in,
                              void* d_out, int out_size, void* d_ws, size_t ws_size,
                              hipStream_t stream) {
    (void)in_sizes; (void)n_in; (void)out_size; (void)ws_size;
    const float* boxes  = (const float*)d_in[0];   // [NB, NN, 4]
    const float* scores = (const float*)d_in[1];   // [NB, NC, NN]
    int* out = (int*)d_out;                        // [NB, NC, NN, 3]

    uint32_t* rowbits = (uint32_t*)d_ws;                           // NB*NN*64 u32 = 4.10 MB
    uint64_t* skeys   = (uint64_t*)((char*)d_ws +
                                    (size_t)NB * NN * 64 * sizeof(uint32_t)); // NB*NC*NN u64 = 2.56 MB

    k_iou_bits<<<dim3(NB * 32), dim3(256), 0, stream>>>(boxes, rowbits);
    k_sort   <<<dim3(NB * NC), dim3(1024), 0, stream>>>(scores, skeys);
    k_nms    <<<dim3(NB * NC), dim3(64),  0, stream>>>(skeys, rowbits, out);
}

// Round 7
// 256.337 us; speedup vs baseline: 1.7650x; 1.0625x over previous
//
#include <hip/hip_runtime.h>
#include <stdint.h>

#define NB 8
#define NC 20
#define NN 2000
#define NP 2048
#define NBLK 32          // ceil(NN/64)
#define IOU_THR 0.5f
#define SCORE_THR 0.1f
#define DEPTH 16         // decisions per batch in k_nms (>= typical alive/block)

// ---------------------------------------------------------------------------
// K1: per-batch pairwise IoU bit matrix in UNSORTED index space.
// rowbits[b][i][w] : bit (j&31) of word w=(j>>5) set iff IoU(box_i, box_j) > 0.5
// ---------------------------------------------------------------------------
__global__ __launch_bounds__(256) void k_iou_bits(const float* __restrict__ boxes,
                                                  uint32_t* __restrict__ rowbits) {
#pragma clang fp contract(off)
    int b = blockIdx.x >> 5;          // /32
    int g = blockIdx.x & 31;          // row group of 64
    __shared__ float x1s[NP], y1s[NP], x2s[NP], y2s[NP], ars[NP];
    for (int j = threadIdx.x; j < NP; j += 256) {
        float vx1 = 0.f, vy1 = 0.f, vx2 = 0.f, vy2 = 0.f;
        if (j < NN) {
            const float* p = boxes + ((size_t)b * NN + j) * 4;
            vy1 = p[0]; vx1 = p[1]; vy2 = p[2]; vx2 = p[3];   // [y1,x1,y2,x2]
        }
        x1s[j] = vx1; y1s[j] = vy1; x2s[j] = vx2; y2s[j] = vy2;
        ars[j] = (vx2 - vx1) * (vy2 - vy1);
    }
    __syncthreads();
    int wave = threadIdx.x >> 6;
    int lane = threadIdx.x & 63;
    for (int rr = 0; rr < 16; ++rr) {
        int i = g * 64 + wave * 16 + rr;          // wave-uniform
        if (i >= NN) continue;
        float xi1 = x1s[i], yi1 = y1s[i], xi2 = x2s[i], yi2 = y2s[i], ai = ars[i];
        uint32_t myword = 0;
        for (int jj = 0; jj < 32; ++jj) {
            int j = jj * 64 + lane;
            bool sup = false;
            if (j < NN) {
                float ix1 = fmaxf(xi1, x1s[j]);
                float iy1 = fmaxf(yi1, y1s[j]);
                float ix2 = fminf(xi2, x2s[j]);
                float iy2 = fminf(yi2, y2s[j]);
                float iw = fmaxf(ix2 - ix1, 0.0f);
                float ih = fmaxf(iy2 - iy1, 0.0f);
                float inter = iw * ih;
                float uni = (ai + ars[j]) - inter;
                float iou = inter / fmaxf(uni, 1e-9f);
                sup = iou > IOU_THR;
            }
            unsigned long long m = __ballot(sup);
            if ((lane >> 1) == jj)
                myword = (lane & 1) ? (uint32_t)(m >> 32) : (uint32_t)m;
        }
        rowbits[((size_t)b * NN + i) * 64 + lane] = myword;
    }
}

// ---------------------------------------------------------------------------
// K2: per-(b,c) stable descending-score sort (bitonic in LDS, 1024 threads).
// key = ((0xFFFFFFFF - bits(score)) <<32) | idx ; invalid: (0xFFFFFFFF<<32)|idx.
// Stored sk[0..NN) always has low32 = a real box index (padding sorts past NN).
// ---------------------------------------------------------------------------
__global__ __launch_bounds__(1024) void k_sort(const float* __restrict__ scores,
                                               uint64_t* __restrict__ skeys) {
    int bc = blockIdx.x;
    __shared__ uint64_t keys[NP];
    const float* sc = scores + (size_t)bc * NN;
    for (int i = threadIdx.x; i < NP; i += 1024) {
        uint64_t k;
        if (i < NN) {
            float s = sc[i];
            uint32_t hi = (s > SCORE_THR) ? (0xFFFFFFFFu - __float_as_uint(s))
                                          : 0xFFFFFFFFu;
            k = ((uint64_t)hi << 32) | (uint32_t)i;
        } else {
            k = ~0ull;
        }
        keys[i] = k;
    }
    __syncthreads();
    for (int k = 2; k <= NP; k <<= 1) {
        for (int j = k >> 1; j > 0; j >>= 1) {
            for (int idx = threadIdx.x; idx < NP; idx += 1024) {
                int l = idx ^ j;
                if (l > idx) {
                    uint64_t a = keys[idx], bb = keys[l];
                    bool up = ((idx & k) == 0);
                    if ((a > bb) == up) { keys[idx] = bb; keys[l] = a; }
                }
            }
            __syncthreads();
        }
    }
    for (int i = threadIdx.x; i < NN; i += 1024)
        skeys[(size_t)bc * NN + i] = keys[i];
}

// ---------------------------------------------------------------------------
// K3: greedy scan, ONE WAVE per (b,c).  Round-5 counters showed the serial
// step = (row load 400-900cy when L2-missing) + (8 dependent ds_bpermute
// ~120cy).  Fixes here:
//  (a) rows of the NEXT 64 sorted candidates prefetched into LDS (double-
//      buffered 2x16KB) via global_load_lds while the current block is
//      validated -> critical-path row access becomes a ~150cy ds_read.
//  (b) batch slot indices are wave-uniform -> candidate ord and the
//      suppressed-bit test use v_readlane (~20cy scalar) instead of
//      bpermute.  DEPTH=16 so a typical block (~9 alive) is ONE batch.
//  (c) outputs written in an epilogue (keep-bits packed per lane) so the
//      per-block vmcnt(0) never waits on stores.
// `removed` = suppression bitmap in unsorted space, word `lane` per lane.
// ---------------------------------------------------------------------------
__global__ __launch_bounds__(64) void k_nms(const uint64_t* __restrict__ skeys,
                                            const uint32_t* __restrict__ rowbits,
                                            int* __restrict__ out) {
    __shared__ uint32_t rows[2][64 * 64];          // 2 x 16KB row buffers
    int bid = blockIdx.x;
    int b = bid & 7;                   // same batch -> same XCD (L2 locality)
    int c = bid >> 3;
    int bc = b * NC + c;
    int lane = threadIdx.x;
    const uint32_t* rb = rowbits + (size_t)b * NN * 64;
    const uint64_t* sk = skeys + (size_t)bc * NN;
    int* o = out + (size_t)bc * NN * 3;
    uint32_t removed = 0;
    uint32_t keptacc = 0;              // bit bk: this lane's box in block bk kept

    // ---- prologue: keys block0, prefetch rows block0, issue keys block1 ----
    uint64_t kcur = sk[lane];                       // lane < NN always
    {
        uint32_t ordp = (uint32_t)kcur;             // low32 is a real index
#pragma unroll
        for (int q = 0; q < 16; ++q) {
            uint32_t oo = (uint32_t)__shfl((int)ordp, q * 4 + (lane >> 4));
            const uint32_t* g = rb + (size_t)oo * 64 + (size_t)((lane & 15) * 4);
            __builtin_amdgcn_global_load_lds(
                (const __attribute__((address_space(1))) void*)g,
                (__attribute__((address_space(3))) void*)(&rows[0][0] + q * 256),
                16, 0, 0);
        }
    }
    uint64_t knext = ~0ull;
    { int i1 = 64 + lane; if (i1 < NN) knext = sk[i1]; }

    for (int bk = 0; bk < NBLK; ++bk) {
        // rows[bk&1] + knext are in flight -> drain before use
        asm volatile("s_waitcnt vmcnt(0)" ::: "memory");

        // ---- issue prefetch for block bk+1 (overlaps this block's work) ----
        if (bk + 1 < NBLK) {
            int inx = (bk + 1) * 64 + lane;
            uint32_t ordp = (inx < NN) ? (uint32_t)knext : 0u;
            uint32_t* lb = &rows[(bk + 1) & 1][0];
#pragma unroll
            for (int q = 0; q < 16; ++q) {
                uint32_t oo = (uint32_t)__shfl((int)ordp, q * 4 + (lane >> 4));
                const uint32_t* g = rb + (size_t)oo * 64 + (size_t)((lane & 15) * 4);
                __builtin_amdgcn_global_load_lds(
                    (const __attribute__((address_space(1))) void*)g,
                    (__attribute__((address_space(3))) void*)(lb + q * 256),
                    16, 0, 0);
            }
        }
        uint64_t kfut = ~0ull;
        if (bk + 2 < NBLK) {
            int i2 = (bk + 2) * 64 + lane;
            if (i2 < NN) kfut = sk[i2];
        }

        // ---- process block bk from LDS ----
        const uint32_t* lrow = &rows[bk & 1][0];
        int i = bk * 64 + lane;
        bool inb = i < NN;
        uint32_t ord = (uint32_t)kcur;
        bool valid = inb && ((uint32_t)(kcur >> 32) != 0xFFFFFFFFu);
        uint32_t osafe = valid ? ord : 0u;
        uint32_t wsel = osafe >> 5, bsel = osafe & 31;
        uint32_t w = (uint32_t)__shfl((int)removed, (int)wsel);
        bool alive = valid && !((w >> bsel) & 1u);
        unsigned long long pend = __ballot(alive);
        uint64_t keptmask = 0ull;

        while (pend) {
            int t[DEPTH];
            unsigned long long p = pend;
#pragma unroll
            for (int k = 0; k < DEPTH; ++k) {
                t[k] = p ? __builtin_ctzll(p) : -1;
                if (p) p &= p - 1;
            }
            int t0 = t[0];
            // parallel conflict-free LDS reads of the candidate rows
            uint32_t rw[DEPTH];
#pragma unroll
            for (int k = 0; k < DEPTH; ++k) {
                int ts = (t[k] >= 0) ? t[k] : t0;
                rw[k] = lrow[(unsigned)ts * 64 + lane];
            }
            // candidate box indices via uniform readlane (t[k] is uniform)
            uint32_t r[DEPTH];
#pragma unroll
            for (int k = 0; k < DEPTH; ++k) {
                int ts = (t[k] >= 0) ? t[k] : t0;
                r[k] = (uint32_t)__builtin_amdgcn_readlane((int)ord, ts);
            }
            uint32_t acc = rw[0];                  // first alive is provably kept
            keptmask |= 1ull << t0;
            int tlast = t0;
#pragma unroll
            for (int k = 1; k < DEPTH; ++k) {
                if (t[k] >= 0) {                   // uniform branch
                    uint32_t wv = (uint32_t)__builtin_amdgcn_readlane(
                        (int)acc, (int)(r[k] >> 5));
                    if (!((wv >> (r[k] & 31)) & 1u)) {    // survived batch keeps
                        acc |= rw[k];
                        keptmask |= 1ull << t[k];
                    }
                    tlast = t[k];                  // decided either way
                }
            }
            removed |= acc;
            w = (uint32_t)__shfl((int)removed, (int)wsel);
            alive = valid && !((w >> bsel) & 1u) && (lane > tlast);
            pend = __ballot(alive);
        }
        if ((keptmask >> lane) & 1ull) keptacc |= 1u << bk;
        kcur = knext;
        knext = kfut;
    }

    // ---- epilogue: write outputs (keys re-read; loads pipeline freely) ----
    for (int bk = 0; bk < NBLK; ++bk) {
        int i = bk * 64 + lane;
        if (i < NN) {
            uint32_t ord = (uint32_t)sk[i];
            bool kept = (keptacc >> bk) & 1u;
            int base = i * 3;
            o[base + 0] = kept ? b : -1;
            o[base + 1] = kept ? c : -1;
            o[base + 2] = kept ? (int)ord : -1;
        }
    }
}

// ---------------------------------------------------------------------------
extern "C" void kernel_launch(void* const* d_in, const int* in_sizes, int n_in,
                              void* d_out, int out_size, void* d_ws, size_t ws_size,
                              hipStream_t stream) {
    (void)in_sizes; (void)n_in; (void)out_size; (void)ws_size;
    const float* boxes  = (const float*)d_in[0];   // [NB, NN, 4]
    const float* scores = (const float*)d_in[1];   // [NB, NC, NN]
    int* out = (int*)d_out;                        // [NB, NC, NN, 3]

    uint32_t* rowbits = (uint32_t*)d_ws;                           // 4.10 MB
    uint64_t* skeys   = (uint64_t*)((char*)d_ws +
                                    (size_t)NB * NN * 64 * sizeof(uint32_t)); // 2.56 MB

    k_iou_bits<<<dim3(NB * 32), dim3(256), 0, stream>>>(boxes, rowbits);
    k_sort   <<<dim3(NB * NC), dim3(1024), 0, stream>>>(scores, skeys);
    k_nms    <<<dim3(NB * NC), dim3(64),  0, stream>>>(skeys, rowbits, out);
}

// Round 10
// 243.998 us; speedup vs baseline: 1.8542x; 1.0506x over previous
//
#include <hip/hip_runtime.h>
#include <stdint.h>

#define NB 8
#define NC 20
#define NN 2000
#define NP 2048
#define NBLK 32          // ceil(NN/64)
#define IOU_THR 0.5f
#define SCORE_THR 0.1f

// ---------------------------------------------------------------------------
// K1: per-batch pairwise IoU bit matrix in UNSORTED index space.
// rowbits[b][i][w] : bit (j&31) of word w=(j>>5) set iff IoU(box_i, box_j) > 0.5
// ---------------------------------------------------------------------------
__global__ __launch_bounds__(256) void k_iou_bits(const float* __restrict__ boxes,
                                                  uint32_t* __restrict__ rowbits) {
#pragma clang fp contract(off)
    int b = blockIdx.x >> 5;          // /32
    int g = blockIdx.x & 31;          // row group of 64
    __shared__ float x1s[NP], y1s[NP], x2s[NP], y2s[NP], ars[NP];
    for (int j = threadIdx.x; j < NP; j += 256) {
        float vx1 = 0.f, vy1 = 0.f, vx2 = 0.f, vy2 = 0.f;
        if (j < NN) {
            const float* p = boxes + ((size_t)b * NN + j) * 4;
            vy1 = p[0]; vx1 = p[1]; vy2 = p[2]; vx2 = p[3];   // [y1,x1,y2,x2]
        }
        x1s[j] = vx1; y1s[j] = vy1; x2s[j] = vx2; y2s[j] = vy2;
        ars[j] = (vx2 - vx1) * (vy2 - vy1);
    }
    __syncthreads();
    int wave = threadIdx.x >> 6;
    int lane = threadIdx.x & 63;
    for (int rr = 0; rr < 16; ++rr) {
        int i = g * 64 + wave * 16 + rr;          // wave-uniform
        if (i >= NN) continue;
        float xi1 = x1s[i], yi1 = y1s[i], xi2 = x2s[i], yi2 = y2s[i], ai = ars[i];
        uint32_t myword = 0;
        for (int jj = 0; jj < 32; ++jj) {
            int j = jj * 64 + lane;
            bool sup = false;
            if (j < NN) {
                float ix1 = fmaxf(xi1, x1s[j]);
                float iy1 = fmaxf(yi1, y1s[j]);
                float ix2 = fminf(xi2, x2s[j]);
                float iy2 = fminf(yi2, y2s[j]);
                float iw = fmaxf(ix2 - ix1, 0.0f);
                float ih = fmaxf(iy2 - iy1, 0.0f);
                float inter = iw * ih;
                float uni = (ai + ars[j]) - inter;
                float iou = inter / fmaxf(uni, 1e-9f);
                sup = iou > IOU_THR;
            }
            unsigned long long m = __ballot(sup);
            if ((lane >> 1) == jj)
                myword = (lane & 1) ? (uint32_t)(m >> 32) : (uint32_t)m;
        }
        rowbits[((size_t)b * NN + i) * 64 + lane] = myword;
    }
}

// ---------------------------------------------------------------------------
// K2: per-(b,c) stable descending-score sort (bitonic in LDS, 1024 threads).
// key = ((0xFFFFFFFF - bits(score)) <<32) | idx ; invalid: (0xFFFFFFFF<<32)|idx.
// Stored sk[0..NN) always has low32 = a real box index (padding sorts past NN).
// ---------------------------------------------------------------------------
__global__ __launch_bounds__(1024) void k_sort(const float* __restrict__ scores,
                                               uint64_t* __restrict__ skeys) {
    int bc = blockIdx.x;
    __shared__ uint64_t keys[NP];
    const float* sc = scores + (size_t)bc * NN;
    for (int i = threadIdx.x; i < NP; i += 1024) {
        uint64_t k;
        if (i < NN) {
            float s = sc[i];
            uint32_t hi = (s > SCORE_THR) ? (0xFFFFFFFFu - __float_as_uint(s))
                                          : 0xFFFFFFFFu;
            k = ((uint64_t)hi << 32) | (uint32_t)i;
        } else {
            k = ~0ull;
        }
        keys[i] = k;
    }
    __syncthreads();
    for (int k = 2; k <= NP; k <<= 1) {
        for (int j = k >> 1; j > 0; j >>= 1) {
            for (int idx = threadIdx.x; idx < NP; idx += 1024) {
                int l = idx ^ j;
                if (l > idx) {
                    uint64_t a = keys[idx], bb = keys[l];
                    bool up = ((idx & k) == 0);
                    if ((a > bb) == up) { keys[idx] = bb; keys[l] = a; }
                }
            }
            __syncthreads();
        }
    }
    for (int i = threadIdx.x; i < NN; i += 1024)
        skeys[(size_t)bc * NN + i] = keys[i];
}

// ---------------------------------------------------------------------------
// K3: greedy scan, ONE WAVE per (b,c).
// Round-7 counters: rows are LDS-resident when needed (FETCH 3.3MB, 96%
// cache-served) but ~7000cy/block went into the serial batch-validation
// (readlane chains). This version replaces it with:
//  (1) 64x64 in-block suppression matrix, built fully in parallel: lane s
//      gathers word (ord_s>>5) of all 64 prefetched rows (ds_read imm
//      offsets) and packs sup_s = {u<s : row_u suppresses box_s}.
//  (2) Multi-round closure, all-uniform ops: lane ready when no UNDECIDED
//      suppressor (sup&undec==0); ready lanes decide kept iff sup&kept==0.
//      Simultaneously-ready lanes cannot suppress each other (a suppressor
//      of a ready lane is decided by definition), >=1 lane decides/round,
//      rounds = chain depth (~3-5). ~80cy/round vs ~1500cy/batch before.
//  (3) kept rows OR'd into `removed` (unsorted-space bitmap, word per lane).
// Prefetch (double-buffered global_load_lds) and epilogue unchanged.
// ---------------------------------------------------------------------------
__global__ __launch_bounds__(64) void k_nms(const uint64_t* __restrict__ skeys,
                                            const uint32_t* __restrict__ rowbits,
                                            int* __restrict__ out) {
    __shared__ uint32_t rows[2][64 * 64];          // 2 x 16KB row buffers
    int bid = blockIdx.x;
    int b = bid & 7;                   // same batch -> same XCD (L2 locality)
    int c = bid >> 3;
    int bc = b * NC + c;
    int lane = threadIdx.x;
    const uint32_t* rb = rowbits + (size_t)b * NN * 64;
    const uint64_t* sk = skeys + (size_t)bc * NN;
    int* o = out + (size_t)bc * NN * 3;
    uint32_t removed = 0;
    uint32_t keptacc = 0;              // bit bk: this lane's box in block bk kept

    // ---- prologue: keys block0, prefetch rows block0, issue keys block1 ----
    uint64_t kcur = sk[lane];                       // lane < NN always
    {
        uint32_t ordp = (uint32_t)kcur;             // low32 is a real index
#pragma unroll
        for (int q = 0; q < 16; ++q) {
            uint32_t oo = (uint32_t)__shfl((int)ordp, q * 4 + (lane >> 4));
            const uint32_t* g = rb + (size_t)oo * 64 + (size_t)((lane & 15) * 4);
            __builtin_amdgcn_global_load_lds(
                (const __attribute__((address_space(1))) void*)g,
                (__attribute__((address_space(3))) void*)(&rows[0][0] + q * 256),
                16, 0, 0);
        }
    }
    uint64_t knext = ~0ull;
    { int i1 = 64 + lane; if (i1 < NN) knext = sk[i1]; }

    for (int bk = 0; bk < NBLK; ++bk) {
        // rows[bk&1] + knext are in flight -> drain before use
        asm volatile("s_waitcnt vmcnt(0)" ::: "memory");

        // ---- issue prefetch for block bk+1 (overlaps this block's work) ----
        if (bk + 1 < NBLK) {
            int inx = (bk + 1) * 64 + lane;
            uint32_t ordp = (inx < NN) ? (uint32_t)knext : 0u;
            uint32_t* lb = &rows[(bk + 1) & 1][0];
#pragma unroll
            for (int q = 0; q < 16; ++q) {
                uint32_t oo = (uint32_t)__shfl((int)ordp, q * 4 + (lane >> 4));
                const uint32_t* g = rb + (size_t)oo * 64 + (size_t)((lane & 15) * 4);
                __builtin_amdgcn_global_load_lds(
                    (const __attribute__((address_space(1))) void*)g,
                    (__attribute__((address_space(3))) void*)(lb + q * 256),
                    16, 0, 0);
            }
        }
        uint64_t kfut = ~0ull;
        if (bk + 2 < NBLK) {
            int i2 = (bk + 2) * 64 + lane;
            if (i2 < NN) kfut = sk[i2];
        }

        // ---- process block bk from LDS ----
        const uint32_t* lrow = &rows[bk & 1][0];
        int i = bk * 64 + lane;
        bool inb = i < NN;
        uint32_t ord = (uint32_t)kcur;
        bool valid = inb && ((uint32_t)(kcur >> 32) != 0xFFFFFFFFu);
        uint32_t osafe = valid ? ord : 0u;
        uint32_t ws = osafe >> 5, bs = osafe & 31;
        uint32_t w = (uint32_t)__shfl((int)removed, (int)ws);
        bool alive0 = valid && !((w >> bs) & 1u);

        // (1) build sup_s: bit u set iff slot-u's row suppresses my box
        const uint32_t* myw = lrow + ws;           // element ws; stride 64 words
        uint32_t lo = 0, hi = 0;
#pragma unroll
        for (int u = 0; u < 32; ++u) {
            uint32_t wrd = myw[u * 64];
            lo |= ((wrd >> bs) & 1u) << u;
        }
#pragma unroll
        for (int u = 0; u < 32; ++u) {
            uint32_t wrd = myw[(u + 32) * 64];
            hi |= ((wrd >> bs) & 1u) << u;
        }
        uint64_t sup = ((uint64_t)hi << 32) | lo;
        sup &= (1ull << lane) - 1ull;              // only earlier slots u < s

        // (2) closure
        unsigned long long undec = __ballot(alive0);
        uint64_t kept64 = 0ull;
        while (undec) {
            bool mine  = (undec >> lane) & 1ull;
            bool ready = mine && ((sup & undec) == 0ull);
            bool kp    = ready && ((sup & kept64) == 0ull);
            unsigned long long readym = __ballot(ready);
            unsigned long long kpm    = __ballot(kp);
            kept64 |= kpm;
            undec &= ~readym;
        }

        // (3) apply kept rows to the cross-block suppression bitmap
        uint64_t km = kept64;
        while (km) {
            int u = __builtin_ctzll(km);
            km &= km - 1;
            removed |= lrow[(unsigned)u * 64 + lane];
        }
        if ((kept64 >> lane) & 1ull) keptacc |= 1u << bk;
        kcur = knext;
        knext = kfut;
    }

    // ---- epilogue: write outputs (keys re-read; loads pipeline freely) ----
    for (int bk = 0; bk < NBLK; ++bk) {
        int i = bk * 64 + lane;
        if (i < NN) {
            uint32_t ord = (uint32_t)sk[i];
            bool kept = (keptacc >> bk) & 1u;
            int base = i * 3;
            o[base + 0] = kept ? b : -1;
            o[base + 1] = kept ? c : -1;
            o[base + 2] = kept ? (int)ord : -1;
        }
    }
}

// ---------------------------------------------------------------------------
extern "C" void kernel_launch(void* const* d_in, const int* in_sizes, int n_in,
                              void* d_out, int out_size, void* d_ws, size_t ws_size,
                              hipStream_t stream) {
    (void)in_sizes; (void)n_in; (void)out_size; (void)ws_size;
    const float* boxes  = (const float*)d_in[0];   // [NB, NN, 4]
    const float* scores = (const float*)d_in[1];   // [NB, NC, NN]
    int* out = (int*)d_out;                        // [NB, NC, NN, 3]

    uint32_t* rowbits = (uint32_t*)d_ws;                           // 4.10 MB
    uint64_t* skeys   = (uint64_t*)((char*)d_ws +
                                    (size_t)NB * NN * 64 * sizeof(uint32_t)); // 2.56 MB

    k_iou_bits<<<dim3(NB * 32), dim3(256), 0, stream>>>(boxes, rowbits);
    k_sort   <<<dim3(NB * NC), dim3(1024), 0, stream>>>(scores, skeys);
    k_nms    <<<dim3(NB * NC), dim3(64),  0, stream>>>(skeys, rowbits, out);
}

// Round 15
// 194.679 us; speedup vs baseline: 2.3240x; 1.2533x over previous
//
#include <hip/hip_runtime.h>
#include <stdint.h>

#define NB 8
#define NC 20
#define NN 2000
#define NP 2048
#define NBLK 32          // ceil(NN/64) for k_nms
#define RG 125           // row groups per batch in k_iou (2000/16)
#define IOU_THR 0.5f
#define SCORE_THR 0.1f

// ---------------------------------------------------------------------------
// K1: per-batch pairwise IoU bit matrix in UNSORTED index space.
// rowbits[b][i][w] : bit (j&31) of word w=(j>>5) set iff IoU(box_i, box_j) > 0.5
// Round-10 counters: 256 blocks = 1 block/CU -> 9.5% occupancy, VALUBusy 32%,
// 5 scalar ds_reads/candidate. Now: 16 rows/block (1000 blocks, ~4/CU, 50%
// occupancy target) + float4 LDS (1 ds_read_b128 + 1 b32 per candidate).
// Padding entries are zero boxes: inter=0, union=area_i>0, iou=0 -> no branch.
// ---------------------------------------------------------------------------
__global__ __launch_bounds__(256) void k_iou_bits(const float* __restrict__ boxes,
                                                  uint32_t* __restrict__ rowbits) {
#pragma clang fp contract(off)
    int b = blockIdx.x / RG;
    int g = blockIdx.x % RG;          // row group of 16
    __shared__ float4 bx[NP];         // (x1,y1,x2,y2), 32KB
    __shared__ float ars[NP];         // areas, 8KB
    for (int j = threadIdx.x; j < NP; j += 256) {
        float4 v = make_float4(0.f, 0.f, 0.f, 0.f);
        if (j < NN) {
            const float4 p = *reinterpret_cast<const float4*>(boxes + ((size_t)b * NN + j) * 4);
            v = make_float4(p.y, p.x, p.w, p.z);   // [y1,x1,y2,x2] -> x1,y1,x2,y2
        }
        bx[j] = v;
        ars[j] = (v.z - v.x) * (v.w - v.y);
    }
    __syncthreads();
    int wave = threadIdx.x >> 6;
    int lane = threadIdx.x & 63;
    for (int rr = 0; rr < 4; ++rr) {
        int i = g * 16 + wave * 4 + rr;           // wave-uniform, always < NN
        float4 bi = bx[i];
        float ai = ars[i];
        uint32_t myword = 0;
        for (int jj = 0; jj < 32; ++jj) {
            int j = jj * 64 + lane;
            float4 bj = bx[j];
            float aj = ars[j];
            float ix1 = fmaxf(bi.x, bj.x);
            float iy1 = fmaxf(bi.y, bj.y);
            float ix2 = fminf(bi.z, bj.z);
            float iy2 = fminf(bi.w, bj.w);
            float iw = fmaxf(ix2 - ix1, 0.0f);
            float ih = fmaxf(iy2 - iy1, 0.0f);
            float inter = iw * ih;
            float uni = (ai + aj) - inter;
            float iou = inter / fmaxf(uni, 1e-9f);   // IEEE div: bit-exact vs ref
            bool sup = iou > IOU_THR;
            unsigned long long m = __ballot(sup); // bits for j = jj*64 .. jj*64+63
            if ((lane >> 1) == jj)                // lanes 2jj, 2jj+1 keep the halves
                myword = (lane & 1) ? (uint32_t)(m >> 32) : (uint32_t)m;
        }
        rowbits[((size_t)b * NN + i) * 64 + lane] = myword;
    }
}

// ---------------------------------------------------------------------------
// K2: per-(b,c) stable descending-score sort (bitonic in LDS, 1024 threads).
// key = ((0xFFFFFFFF - bits(score)) <<32) | idx ; invalid: (0xFFFFFFFF<<32)|idx.
// Stored sk[0..NN) always has low32 = a real box index (padding sorts past NN).
// ---------------------------------------------------------------------------
__global__ __launch_bounds__(1024) void k_sort(const float* __restrict__ scores,
                                               uint64_t* __restrict__ skeys) {
    int bc = blockIdx.x;
    __shared__ uint64_t keys[NP];
    const float* sc = scores + (size_t)bc * NN;
    for (int i = threadIdx.x; i < NP; i += 1024) {
        uint64_t k;
        if (i < NN) {
            float s = sc[i];
            uint32_t hi = (s > SCORE_THR) ? (0xFFFFFFFFu - __float_as_uint(s))
                                          : 0xFFFFFFFFu;
            k = ((uint64_t)hi << 32) | (uint32_t)i;
        } else {
            k = ~0ull;
        }
        keys[i] = k;
    }
    __syncthreads();
    for (int k = 2; k <= NP; k <<= 1) {
        for (int j = k >> 1; j > 0; j >>= 1) {
            for (int idx = threadIdx.x; idx < NP; idx += 1024) {
                int l = idx ^ j;
                if (l > idx) {
                    uint64_t a = keys[idx], bb = keys[l];
                    bool up = ((idx & k) == 0);
                    if ((a > bb) == up) { keys[idx] = bb; keys[l] = a; }
                }
            }
            __syncthreads();
        }
    }
    for (int i = threadIdx.x; i < NN; i += 1024)
        skeys[(size_t)bc * NN + i] = keys[i];
}

// ---------------------------------------------------------------------------
// K3: greedy scan, ONE WAVE per (b,c).  (verified round 10: dropped below
// top-5, was 93us with readlane chains, now closure-based)
//  (1) 64x64 in-block suppression matrix built in parallel from prefetched
//      rows (lane s gathers word ord_s>>5 of each row, packs sup_s).
//  (2) Multi-round uniform closure: ready when no undecided suppressor;
//      ready lanes decide kept iff sup&kept==0. >=1 decision/round.
//  (3) kept rows OR'd into `removed` (unsorted-space bitmap, word per lane).
// Double-buffered global_load_lds prefetch of next 64 sorted rows.
// ---------------------------------------------------------------------------
__global__ __launch_bounds__(64) void k_nms(const uint64_t* __restrict__ skeys,
                                            const uint32_t* __restrict__ rowbits,
                                            int* __restrict__ out) {
    __shared__ uint32_t rows[2][64 * 64];          // 2 x 16KB row buffers
    int bid = blockIdx.x;
    int b = bid & 7;                   // same batch -> same XCD (L2 locality)
    int c = bid >> 3;
    int bc = b * NC + c;
    int lane = threadIdx.x;
    const uint32_t* rb = rowbits + (size_t)b * NN * 64;
    const uint64_t* sk = skeys + (size_t)bc * NN;
    int* o = out + (size_t)bc * NN * 3;
    uint32_t removed = 0;
    uint32_t keptacc = 0;              // bit bk: this lane's box in block bk kept

    // ---- prologue: keys block0, prefetch rows block0, issue keys block1 ----
    uint64_t kcur = sk[lane];                       // lane < NN always
    {
        uint32_t ordp = (uint32_t)kcur;             // low32 is a real index
#pragma unroll
        for (int q = 0; q < 16; ++q) {
            uint32_t oo = (uint32_t)__shfl((int)ordp, q * 4 + (lane >> 4));
            const uint32_t* g = rb + (size_t)oo * 64 + (size_t)((lane & 15) * 4);
            __builtin_amdgcn_global_load_lds(
                (const __attribute__((address_space(1))) void*)g,
                (__attribute__((address_space(3))) void*)(&rows[0][0] + q * 256),
                16, 0, 0);
        }
    }
    uint64_t knext = ~0ull;
    { int i1 = 64 + lane; if (i1 < NN) knext = sk[i1]; }

    for (int bk = 0; bk < NBLK; ++bk) {
        // rows[bk&1] + knext are in flight -> drain before use
        asm volatile("s_waitcnt vmcnt(0)" ::: "memory");

        // ---- issue prefetch for block bk+1 (overlaps this block's work) ----
        if (bk + 1 < NBLK) {
            int inx = (bk + 1) * 64 + lane;
            uint32_t ordp = (inx < NN) ? (uint32_t)knext : 0u;
            uint32_t* lb = &rows[(bk + 1) & 1][0];
#pragma unroll
            for (int q = 0; q < 16; ++q) {
                uint32_t oo = (uint32_t)__shfl((int)ordp, q * 4 + (lane >> 4));
                const uint32_t* g = rb + (size_t)oo * 64 + (size_t)((lane & 15) * 4);
                __builtin_amdgcn_global_load_lds(
                    (const __attribute__((address_space(1))) void*)g,
                    (__attribute__((address_space(3))) void*)(lb + q * 256),
                    16, 0, 0);
            }
        }
        uint64_t kfut = ~0ull;
        if (bk + 2 < NBLK) {
            int i2 = (bk + 2) * 64 + lane;
            if (i2 < NN) kfut = sk[i2];
        }

        // ---- process block bk from LDS ----
        const uint32_t* lrow = &rows[bk & 1][0];
        int i = bk * 64 + lane;
        bool inb = i < NN;
        uint32_t ord = (uint32_t)kcur;
        bool valid = inb && ((uint32_t)(kcur >> 32) != 0xFFFFFFFFu);
        uint32_t osafe = valid ? ord : 0u;
        uint32_t ws = osafe >> 5, bs = osafe & 31;
        uint32_t w = (uint32_t)__shfl((int)removed, (int)ws);
        bool alive0 = valid && !((w >> bs) & 1u);

        // (1) build sup_s: bit u set iff slot-u's row suppresses my box
        const uint32_t* myw = lrow + ws;           // element ws; stride 64 words
        uint32_t lo = 0, hi = 0;
#pragma unroll
        for (int u = 0; u < 32; ++u) {
            uint32_t wrd = myw[u * 64];
            lo |= ((wrd >> bs) & 1u) << u;
        }
#pragma unroll
        for (int u = 0; u < 32; ++u) {
            uint32_t wrd = myw[(u + 32) * 64];
            hi |= ((wrd >> bs) & 1u) << u;
        }
        uint64_t sup = ((uint64_t)hi << 32) | lo;
        sup &= (1ull << lane) - 1ull;              // only earlier slots u < s

        // (2) closure
        unsigned long long undec = __ballot(alive0);
        uint64_t kept64 = 0ull;
        while (undec) {
            bool mine  = (undec >> lane) & 1ull;
            bool ready = mine && ((sup & undec) == 0ull);
            bool kp    = ready && ((sup & kept64) == 0ull);
            unsigned long long readym = __ballot(ready);
            unsigned long long kpm    = __ballot(kp);
            kept64 |= kpm;
            undec &= ~readym;
        }

        // (3) apply kept rows to the cross-block suppression bitmap
        uint64_t km = kept64;
        while (km) {
            int u = __builtin_ctzll(km);
            km &= km - 1;
            removed |= lrow[(unsigned)u * 64 + lane];
        }
        if ((kept64 >> lane) & 1ull) keptacc |= 1u << bk;
        kcur = knext;
        knext = kfut;
    }

    // ---- epilogue: write outputs (keys re-read; loads pipeline freely) ----
    for (int bk = 0; bk < NBLK; ++bk) {
        int i = bk * 64 + lane;
        if (i < NN) {
            uint32_t ord = (uint32_t)sk[i];
            bool kept = (keptacc >> bk) & 1u;
            int base = i * 3;
            o[base + 0] = kept ? b : -1;
            o[base + 1] = kept ? c : -1;
            o[base + 2] = kept ? (int)ord : -1;
        }
    }
}

// ---------------------------------------------------------------------------
extern "C" void kernel_launch(void* const* d_in, const int* in_sizes, int n_in,
                              void* d_out, int out_size, void* d_ws, size_t ws_size,
                              hipStream_t stream) {
    (void)in_sizes; (void)n_in; (void)out_size; (void)ws_size;
    const float* boxes  = (const float*)d_in[0];   // [NB, NN, 4]
    const float* scores = (const float*)d_in[1];   // [NB, NC, NN]
    int* out = (int*)d_out;                        // [NB, NC, NN, 3]

    uint32_t* rowbits = (uint32_t*)d_ws;                           // 4.10 MB
    uint64_t* skeys   = (uint64_t*)((char*)d_ws +
                                    (size_t)NB * NN * 64 * sizeof(uint32_t)); // 2.56 MB

    k_iou_bits<<<dim3(NB * RG), dim3(256), 0, stream>>>(boxes, rowbits);
    k_sort   <<<dim3(NB * NC), dim3(1024), 0, stream>>>(scores, skeys);
    k_nms    <<<dim3(NB * NC), dim3(64),  0, stream>>>(skeys, rowbits, out);
}

// Round 16
// 180.390 us; speedup vs baseline: 2.5081x; 1.0792x over previous
//
#include <hip/hip_runtime.h>
#include <stdint.h>

#define NB 8
#define NC 20
#define NN 2000
#define NP 2048
#define NBLK 32          // ceil(NN/64) for k_nms
#define RG 125           // row groups per batch in k_iou (2000/16)
#define IOU_THR 0.5f
#define SCORE_THR 0.1f

// ---------------------------------------------------------------------------
// K1: per-batch pairwise IoU bit matrix in UNSORTED index space.
// rowbits[b][i][w] : bit (j&31) of word w=(j>>5) set iff IoU(box_i, box_j) > 0.5
// (verified round 15: left top-5 after 16-rows/block + float4-LDS fix)
// ---------------------------------------------------------------------------
__global__ __launch_bounds__(256) void k_iou_bits(const float* __restrict__ boxes,
                                                  uint32_t* __restrict__ rowbits) {
#pragma clang fp contract(off)
    int b = blockIdx.x / RG;
    int g = blockIdx.x % RG;          // row group of 16
    __shared__ float4 bx[NP];         // (x1,y1,x2,y2), 32KB
    __shared__ float ars[NP];         // areas, 8KB
    for (int j = threadIdx.x; j < NP; j += 256) {
        float4 v = make_float4(0.f, 0.f, 0.f, 0.f);
        if (j < NN) {
            const float4 p = *reinterpret_cast<const float4*>(boxes + ((size_t)b * NN + j) * 4);
            v = make_float4(p.y, p.x, p.w, p.z);   // [y1,x1,y2,x2] -> x1,y1,x2,y2
        }
        bx[j] = v;
        ars[j] = (v.z - v.x) * (v.w - v.y);
    }
    __syncthreads();
    int wave = threadIdx.x >> 6;
    int lane = threadIdx.x & 63;
    for (int rr = 0; rr < 4; ++rr) {
        int i = g * 16 + wave * 4 + rr;           // wave-uniform, always < NN
        float4 bi = bx[i];
        float ai = ars[i];
        uint32_t myword = 0;
        for (int jj = 0; jj < 32; ++jj) {
            int j = jj * 64 + lane;
            float4 bj = bx[j];
            float aj = ars[j];
            float ix1 = fmaxf(bi.x, bj.x);
            float iy1 = fmaxf(bi.y, bj.y);
            float ix2 = fminf(bi.z, bj.z);
            float iy2 = fminf(bi.w, bj.w);
            float iw = fmaxf(ix2 - ix1, 0.0f);
            float ih = fmaxf(iy2 - iy1, 0.0f);
            float inter = iw * ih;
            float uni = (ai + aj) - inter;
            float iou = inter / fmaxf(uni, 1e-9f);   // IEEE div: bit-exact vs ref
            bool sup = iou > IOU_THR;
            unsigned long long m = __ballot(sup);
            if ((lane >> 1) == jj)
                myword = (lane & 1) ? (uint32_t)(m >> 32) : (uint32_t)m;
        }
        rowbits[((size_t)b * NN + i) * 64 + lane] = myword;
    }
}

// ---------------------------------------------------------------------------
// K2: per-(b,c) stable descending-score sort, REGISTER bitonic.
// Same network & keys as before (stability via unique (score,idx) keys);
// execution moved to registers: 2 elements/thread (e0=elem 2t, e1=elem 2t+1),
//   j == 1      : in-thread compare-exchange
//   j == 2..64  : __shfl_xor(m=j/2 <= 32, within wave64), no barrier
//   j >= 128    : LDS + 2 barriers (only 10 such stages vs 66 before)
// key = ((0xFFFFFFFF - bits(score)) <<32) | idx ; invalid: (0xFFFFFFFF<<32)|idx.
// ---------------------------------------------------------------------------
__device__ __forceinline__ uint64_t sort_key(const float* sc, int i) {
    if (i < NN) {
        float s = sc[i];
        uint32_t hi = (s > SCORE_THR) ? (0xFFFFFFFFu - __float_as_uint(s))
                                      : 0xFFFFFFFFu;
        return ((uint64_t)hi << 32) | (uint32_t)i;
    }
    return ~0ull;
}

__global__ __launch_bounds__(1024) void k_sort(const float* __restrict__ scores,
                                               uint64_t* __restrict__ skeys) {
    int bc = blockIdx.x;
    int t = threadIdx.x;
    __shared__ uint64_t keys[NP];
    const float* sc = scores + (size_t)bc * NN;
    uint64_t e0 = sort_key(sc, 2 * t);
    uint64_t e1 = sort_key(sc, 2 * t + 1);

    for (int k = 2; k <= NP; k <<= 1) {
        for (int j = k >> 1; j > 0; j >>= 1) {
            bool up = (((2 * t) & k) == 0);        // same for both elements (k>=2)
            if (j >= 128) {
                // cross-wave: through LDS
                keys[2 * t] = e0;
                keys[2 * t + 1] = e1;
                __syncthreads();
                uint64_t p0 = keys[(2 * t) ^ j];
                uint64_t p1 = keys[(2 * t + 1) ^ j];
                bool lower = (((2 * t) & j) == 0); // same for both (j>=2)
                e0 = (lower == up) ? (e0 < p0 ? e0 : p0) : (e0 > p0 ? e0 : p0);
                e1 = (lower == up) ? (e1 < p1 ? e1 : p1) : (e1 > p1 ? e1 : p1);
                __syncthreads();
            } else if (j >= 2) {
                // within-wave: shfl_xor, partner thread t^(j/2), same register
                int m = j >> 1;
                uint64_t p0 = __shfl_xor((unsigned long long)e0, m, 64);
                uint64_t p1 = __shfl_xor((unsigned long long)e1, m, 64);
                bool lower = ((t & m) == 0);
                e0 = (lower == up) ? (e0 < p0 ? e0 : p0) : (e0 > p0 ? e0 : p0);
                e1 = (lower == up) ? (e1 < p1 ? e1 : p1) : (e1 > p1 ? e1 : p1);
            } else {
                // j == 1: both elements in-thread (e0 = lower index)
                if (up ? (e0 > e1) : (e0 < e1)) { uint64_t tmp = e0; e0 = e1; e1 = tmp; }
            }
        }
    }
    int i0 = 2 * t;
    if (i0 < NN)     skeys[(size_t)bc * NN + i0] = e0;
    if (i0 + 1 < NN) skeys[(size_t)bc * NN + i0 + 1] = e1;
}

// ---------------------------------------------------------------------------
// K3: greedy scan, ONE WAVE per (b,c), closure-based (round 10).
// Round-15 counters: VALUBusy/active-wave ~4.5% -> ~95% stall; 88 VGPRs ->
// compiler can't keep the 64 gather ds_reads in flight (latency paid ~8x).
// Fixes: __launch_bounds__(64,1) (512-VGPR budget) + two-phase gather
// (issue ALL 64 reads into statically-indexed regs, then extract bits).
// ---------------------------------------------------------------------------
__global__ __launch_bounds__(64, 1) void k_nms(const uint64_t* __restrict__ skeys,
                                               const uint32_t* __restrict__ rowbits,
                                               int* __restrict__ out) {
    __shared__ uint32_t rows[2][64 * 64];          // 2 x 16KB row buffers
    int bid = blockIdx.x;
    int b = bid & 7;                   // same batch -> same XCD (L2 locality)
    int c = bid >> 3;
    int bc = b * NC + c;
    int lane = threadIdx.x;
    const uint32_t* rb = rowbits + (size_t)b * NN * 64;
    const uint64_t* sk = skeys + (size_t)bc * NN;
    int* o = out + (size_t)bc * NN * 3;
    uint32_t removed = 0;
    uint32_t keptacc = 0;              // bit bk: this lane's box in block bk kept

    // ---- prologue: keys block0, prefetch rows block0, issue keys block1 ----
    uint64_t kcur = sk[lane];                       // lane < NN always
    {
        uint32_t ordp = (uint32_t)kcur;             // low32 is a real index
#pragma unroll
        for (int q = 0; q < 16; ++q) {
            uint32_t oo = (uint32_t)__shfl((int)ordp, q * 4 + (lane >> 4));
            const uint32_t* g = rb + (size_t)oo * 64 + (size_t)((lane & 15) * 4);
            __builtin_amdgcn_global_load_lds(
                (const __attribute__((address_space(1))) void*)g,
                (__attribute__((address_space(3))) void*)(&rows[0][0] + q * 256),
                16, 0, 0);
        }
    }
    uint64_t knext = ~0ull;
    { int i1 = 64 + lane; if (i1 < NN) knext = sk[i1]; }

    for (int bk = 0; bk < NBLK; ++bk) {
        // rows[bk&1] + knext are in flight -> drain before use
        asm volatile("s_waitcnt vmcnt(0)" ::: "memory");

        // ---- issue prefetch for block bk+1 (overlaps this block's work) ----
        if (bk + 1 < NBLK) {
            int inx = (bk + 1) * 64 + lane;
            uint32_t ordp = (inx < NN) ? (uint32_t)knext : 0u;
            uint32_t* lb = &rows[(bk + 1) & 1][0];
#pragma unroll
            for (int q = 0; q < 16; ++q) {
                uint32_t oo = (uint32_t)__shfl((int)ordp, q * 4 + (lane >> 4));
                const uint32_t* g = rb + (size_t)oo * 64 + (size_t)((lane & 15) * 4);
                __builtin_amdgcn_global_load_lds(
                    (const __attribute__((address_space(1))) void*)g,
                    (__attribute__((address_space(3))) void*)(lb + q * 256),
                    16, 0, 0);
            }
        }
        uint64_t kfut = ~0ull;
        if (bk + 2 < NBLK) {
            int i2 = (bk + 2) * 64 + lane;
            if (i2 < NN) kfut = sk[i2];
        }

        // ---- process block bk from LDS ----
        const uint32_t* lrow = &rows[bk & 1][0];
        int i = bk * 64 + lane;
        bool inb = i < NN;
        uint32_t ord = (uint32_t)kcur;
        bool valid = inb && ((uint32_t)(kcur >> 32) != 0xFFFFFFFFu);
        uint32_t osafe = valid ? ord : 0u;
        uint32_t ws = osafe >> 5, bs = osafe & 31;
        uint32_t w = (uint32_t)__shfl((int)removed, (int)ws);
        bool alive0 = valid && !((w >> bs) & 1u);

        // (1) build sup_s, two-phase: issue ALL 64 reads, then extract.
        const uint32_t* myw = lrow + ws;           // element ws; stride 64 words
        uint32_t wv[64];
#pragma unroll
        for (int u = 0; u < 64; ++u) wv[u] = myw[u * 64];
        uint32_t lo = 0, hi = 0;
#pragma unroll
        for (int u = 0; u < 32; ++u) lo |= ((wv[u] >> bs) & 1u) << u;
#pragma unroll
        for (int u = 0; u < 32; ++u) hi |= ((wv[u + 32] >> bs) & 1u) << u;
        uint64_t sup = ((uint64_t)hi << 32) | lo;
        sup &= (1ull << lane) - 1ull;              // only earlier slots u < s

        // (2) closure
        unsigned long long undec = __ballot(alive0);
        uint64_t kept64 = 0ull;
        while (undec) {
            bool mine  = (undec >> lane) & 1ull;
            bool ready = mine && ((sup & undec) == 0ull);
            bool kp    = ready && ((sup & kept64) == 0ull);
            unsigned long long readym = __ballot(ready);
            unsigned long long kpm    = __ballot(kp);
            kept64 |= kpm;
            undec &= ~readym;
        }

        // (3) apply kept rows to the cross-block suppression bitmap
        uint64_t km = kept64;
        while (km) {
            int u = __builtin_ctzll(km);
            km &= km - 1;
            removed |= lrow[(unsigned)u * 64 + lane];
        }
        if ((kept64 >> lane) & 1ull) keptacc |= 1u << bk;
        kcur = knext;
        knext = kfut;
    }

    // ---- epilogue: write outputs (keys re-read; loads pipeline freely) ----
    for (int bk = 0; bk < NBLK; ++bk) {
        int i = bk * 64 + lane;
        if (i < NN) {
            uint32_t ord = (uint32_t)sk[i];
            bool kept = (keptacc >> bk) & 1u;
            int base = i * 3;
            o[base + 0] = kept ? b : -1;
            o[base + 1] = kept ? c : -1;
            o[base + 2] = kept ? (int)ord : -1;
        }
    }
}

// ---------------------------------------------------------------------------
extern "C" void kernel_launch(void* const* d_in, const int* in_sizes, int n_in,
                              void* d_out, int out_size, void* d_ws, size_t ws_size,
                              hipStream_t stream) {
    (void)in_sizes; (void)n_in; (void)out_size; (void)ws_size;
    const float* boxes  = (const float*)d_in[0];   // [NB, NN, 4]
    const float* scores = (const float*)d_in[1];   // [NB, NC, NN]
    int* out = (int*)d_out;                        // [NB, NC, NN, 3]

    uint32_t* rowbits = (uint32_t*)d_ws;                           // 4.10 MB
    uint64_t* skeys   = (uint64_t*)((char*)d_ws +
                                    (size_t)NB * NN * 64 * sizeof(uint32_t)); // 2.56 MB

    k_iou_bits<<<dim3(NB * RG), dim3(256), 0, stream>>>(boxes, rowbits);
    k_sort   <<<dim3(NB * NC), dim3(1024), 0, stream>>>(scores, skeys);
    k_nms    <<<dim3(NB * NC), dim3(64),  0, stream>>>(skeys, rowbits, out);
}